// Round 2
// 115.345 us; speedup vs baseline: 1.0179x; 1.0179x over previous
//
#include <hip/hip_runtime.h>

// StructureTensorEffect: B=4, C=3, H=W=1024, fp32.
// Round 8b: single-shot async staging (resubmit; R8 bench infra failed).
// R7 (per-channel LDS phases, 44us/dispatch) was latency-bound:
// FETCH/WRITE already ideal (~50MB each), VALUBusy 21%, BW 2.3 of
// 6.3 TB/s. Cause: 3 sequential {load->barrier->compute->barrier}
// phases, each exposing ~900cy HBM latency with MLP ~3. This round:
// stage ALL 3 channels at once via __builtin_amdgcn_global_load_lds
// (16B/lane direct-to-LDS). LDS layout is linear in group index g
// (byte offset g*16) = the required wave-uniform-base + lane*16
// pattern (per-lane clamped GLOBAL address does border replication).
// ~8 async copies/thread back-to-back -> one vmcnt(0)+barrier -> all
// 3 channels computed from LDS with no further barriers.
// Hardened vs R8: staging tail split out so full iterations run with
// uniform exec; divergence confined to one final guarded copy (first
// active lane is lane 0, so the readfirstlane'd LDS base is correct).
// LDS 3*38*72*4 = 32832B -> 4 blocks/CU (16 waves).
// Borders: unchanged R4-proven scheme (store mask + border slice).

#define W_ 1024
#define H_ 1024
#define PLANE (1 << 20)
#define TCOLS 64
#define TROWS 32
#define ROWS 8
#define LSTRIDE 72     // staged cols: x0-4 .. x0+67 (18 float4 groups)

__device__ __forceinline__ float lerp1(float a, float b, float f) {
    return fmaf(f, b - a, a);
}

// async 16B global->LDS copy (gfx950). Dest must be linear in lane order.
__device__ __forceinline__ void async_copy16(const float* g, float* s) {
    __builtin_amdgcn_global_load_lds(
        (const __attribute__((address_space(1))) unsigned int*)g,
        (__attribute__((address_space(3))) unsigned int*)s,
        16, 0, 0);
}

// Exact per-pixel reference path (any sigma, any border) — verified R1-R7.
__device__ void slow_pixel(const float* __restrict__ Xb, float* __restrict__ Ob,
                           float sg, int xi, int y)
{
    float imf = floorf(-sg), ipf = floorf(sg);
    float fm  = -sg - imf;
    float fp  =  sg - ipf;
    int   im  = (int)imf, ip = (int)ipf;

    int cm0 = min(max(xi + im, 0), W_ - 1), cm1 = min(cm0 + 1, W_ - 1);
    int cp0 = min(max(xi + ip, 0), W_ - 1), cp1 = min(cp0 + 1, W_ - 1);
    int rm0 = min(max(y + im, 0), H_ - 1),  rm1 = min(rm0 + 1, H_ - 1);
    int rp0 = min(max(y + ip, 0), H_ - 1),  rp1 = min(rp0 + 1, H_ - 1);

    int o_rm0 = rm0 << 10, o_rm1 = rm1 << 10;
    int o_rp0 = rp0 << 10, o_rp1 = rp1 << 10;
    int o_r0  = y   << 10;

    float oxx = 0.f, oyy = 0.f, oxy = 0.f;

    #pragma unroll
    for (int c = 0; c < 3; ++c) {
        const float* base = Xb + ((size_t)c << 20);

        float hm_m0 = lerp1(base[o_rm0 + cm0], base[o_rm0 + cm1], fm);
        float hm_m1 = lerp1(base[o_rm1 + cm0], base[o_rm1 + cm1], fm);
        float hm_0  = lerp1(base[o_r0  + cm0], base[o_r0  + cm1], fm);
        float hm_p0 = lerp1(base[o_rp0 + cm0], base[o_rp0 + cm1], fm);
        float hm_p1 = lerp1(base[o_rp1 + cm0], base[o_rp1 + cm1], fm);
        float hp_m0 = lerp1(base[o_rm0 + cp0], base[o_rm0 + cp1], fp);
        float hp_m1 = lerp1(base[o_rm1 + cp0], base[o_rm1 + cp1], fp);
        float hp_0  = lerp1(base[o_r0  + cp0], base[o_r0  + cp1], fp);
        float hp_p0 = lerp1(base[o_rp0 + cp0], base[o_rp0 + cp1], fp);
        float hp_p1 = lerp1(base[o_rp1 + cp0], base[o_rp1 + cp1], fp);
        float h0_m0 = base[o_rm0 + xi], h0_m1 = base[o_rm1 + xi];
        float h0_p0 = base[o_rp0 + xi], h0_p1 = base[o_rp1 + xi];

        float t0 = lerp1(hm_m0, hm_m1, fm);
        float t1 = hm_0;
        float t2 = lerp1(hm_p0, hm_p1, fp);
        float t3 = lerp1(h0_m0, h0_m1, fm);
        float t4 = lerp1(h0_p0, h0_p1, fp);
        float t5 = lerp1(hp_m0, hp_m1, fm);
        float t6 = hp_0;
        float t7 = lerp1(hp_p0, hp_p1, fp);

        float su = 0.25f * (t5 + t7 - t0 - t2) + 0.5f * (t6 - t1);
        float sv = 0.25f * (t2 + t7 - t0 - t5) + 0.5f * (t4 - t3);

        float l2 = (c == 0) ? 10000.f : 1.f;
        oxx = fmaf(l2 * su, su, oxx);
        oyy = fmaf(l2 * sv, sv, oyy);
        oxy = fmaf(l2 * su, sv, oxy);
    }

    int pix = (y << 10) | xi;
    Ob[pix]             = oxx;
    Ob[PLANE + pix]     = oyy;
    Ob[2 * PLANE + pix] = oxy;
}

template<int N>
__device__ __forceinline__ void acc(float (&arr)[N], int k, float val) {
    if (k >= 0 && k < N) arr[k] += val;   // k constant after unroll
}

// Fast tile: block covers cols x0..x0+63, rows y0..y0+31.
// Stage ALL channels' clamped windows (rows y0-IP-1..y0+32+IP, cols
// x0-4..x0+67) into LDS via async 16B copies, one barrier, then stream
// the accumulate from LDS for all 3 channels with no further barriers.
// Store mask (x>IP && x<1023-IP && y>IP) excludes clamp-wrong px; those
// are covered by the border slice.
template<int IP>
__device__ void fast_tile(const float* __restrict__ Xb, float* __restrict__ Ob,
                          float fp, float fm, int x0, int y0,
                          int tx, int ty, int tid, float* smem)
{
    constexpr int LROWS  = TROWS + 2 * IP + 2;   // staged rows per channel
    constexpr int RW     = ROWS + 2 * IP + 2;    // window rows per thread
    constexpr int NG     = 3 * LROWS * 18;       // float4 groups, all channels
    constexpr int FULLIT = NG / 256;             // guard-free iterations

    int x = x0 + tx;
    int Y = y0 + ty * ROWS;

    auto stage = [&](int g) {
        int row  = g / 18;             // 0 .. 3*LROWS-1
        int grp  = g - row * 18;
        int c    = row / LROWS;
        int lrow = row - c * LROWS;
        int gr   = min(max(y0 - IP - 1 + lrow, 0), H_ - 1);
        int gc   = min(max(x0 - 4 + grp * 4, 0), W_ - 4);
        async_copy16(Xb + ((size_t)c << 20) + (gr << 10) + gc,
                     smem + g * 4);    // LDS linear in g: lane-contiguous
    };

    // ---- single-shot staging: all channels, direct-to-LDS ----
    #pragma unroll
    for (int it = 0; it < FULLIT; ++it)
        stage(it * 256 + tid);         // uniform exec
    if (FULLIT * 256 + tid < NG)       // single guarded tail copy
        stage(FULLIT * 256 + tid);

    __syncthreads();   // compiler emits vmcnt(0) drain before s_barrier

    float oxx[ROWS], oyy[ROWS], oxy[ROWS];
    #pragma unroll
    for (int k = 0; k < ROWS; ++k) { oxx[k] = 0.f; oyy[k] = 0.f; oxy[k] = 0.f; }

    // thread's LDS read base: window row w of channel c lives at LDS row
    // c*LROWS + ty*ROWS + w; LDS col of global col gcol is gcol-(x0-4);
    // a0 is at col x-IP-1 -> tx + 3 - IP.
    const float* spb = smem + (ty * ROWS) * LSTRIDE + tx + (3 - IP);

    #pragma unroll
    for (int c = 0; c < 3; ++c) {
        const float* sp = spb + c * (LROWS * LSTRIDE);

        float su[ROWS], sv[ROWS];
        #pragma unroll
        for (int k = 0; k < ROWS; ++k) { su[k] = 0.f; sv[k] = 0.f; }

        #pragma unroll
        for (int w = 0; w < RW; ++w) {
            float a0 = sp[w * LSTRIDE];
            float a1 = sp[w * LSTRIDE + 1];
            float cc = sp[w * LSTRIDE + IP + 1];
            float b0 = sp[w * LSTRIDE + 2 * IP + 1];
            float b1 = sp[w * LSTRIDE + 2 * IP + 2];
            float hm = lerp1(a0, a1, fm);
            float hp = lerp1(b0, b1, fp);
            float q  = hp - hm;
            float A  = 0.25f * q;
            float hq = 0.5f  * q;
            float Bv = fmaf(0.25f, hm + hp, 0.5f * cc);
            float fpA = fp * A,  fmA = fm * A;
            float fpB = fp * Bv, fmB = fm * Bv;

            acc(su, w,              fpA);
            acc(su, w - 1,          fmA);
            acc(su, w - IP - 1,     hq);
            acc(su, w - 2*IP - 1,   fmA);
            acc(su, w - 2*IP - 2,   fpA);
            acc(sv, w,             -fpB);
            acc(sv, w - 1,         -fmB);
            acc(sv, w - 2*IP - 1,   fmB);
            acc(sv, w - 2*IP - 2,   fpB);
        }

        float l2 = (c == 0) ? 10000.f : 1.f;
        #pragma unroll
        for (int k = 0; k < ROWS; ++k) {
            oxx[k] = fmaf(l2 * su[k], su[k], oxx[k]);
            oyy[k] = fmaf(l2 * sv[k], sv[k], oyy[k]);
            oxy[k] = fmaf(l2 * su[k], sv[k], oxy[k]);
        }
    }

    bool okx = (x > IP) && (x < W_ - 1 - IP);
    #pragma unroll
    for (int k = 0; k < ROWS; ++k) {
        int y = Y + k;
        if (okx && y > IP) {
            int pix = (y << 10) | x;
            Ob[pix]             = oxx[k];
            Ob[PLANE + pix]     = oyy[k];
            Ob[2 * PLANE + pix] = oxy[k];
        }
    }
}

// block (64,4). grid.y = 32 tile bands + 1 border slice.
__global__ __launch_bounds__(256) void st_kernel(
    const float* __restrict__ X, const float* __restrict__ S,
    float* __restrict__ O)
{
    int b  = blockIdx.z;
    const float* Xb = X + (size_t)b * 3 * PLANE;
    float*       Ob = O + (size_t)b * 3 * PLANE;
    float sg = S[b];

    int tx = threadIdx.x, ty = threadIdx.y;
    int tid = ty * 64 + tx;

    if (blockIdx.y == (H_ / TROWS)) {
        // Border slice: x in {0,1,2,1021,1022,1023} all y (6144 px) plus
        // y in {0,1,2} all x (3072 px). 16*256 = 4096 threads -> 3 iters.
        int t = blockIdx.x * 256 + tid;
        #pragma unroll
        for (int it = 0; it < 3; ++it) {
            int pidx = t + it * 4096;
            if (pidx < 6144) {
                int yy = pidx / 6;
                int cc = pidx - yy * 6;
                int xx = (cc < 3) ? cc : (W_ - 6 + cc);
                slow_pixel(Xb, Ob, sg, xx, yy);
            } else if (pidx < 9216) {
                int p2 = pidx - 6144;
                slow_pixel(Xb, Ob, sg, p2 & 1023, p2 >> 10);
            }
        }
        return;
    }

    int x0 = blockIdx.x * TCOLS;
    int y0 = blockIdx.y * TROWS;

    int ipv = (int)floorf(sg);
    int imv = (int)floorf(-sg);
    bool sig_ok = (imv == -ipv - 1) && ipv >= 0 && ipv <= 2;  // block-uniform
    float fp = sg - (float)ipv;
    float fm = 1.0f - fp;

    // worst case IP=2: 3 channels x 38 rows x 72 cols = 32832 B -> 4 blk/CU
    __shared__ float smem[3 * (TROWS + 6) * LSTRIDE];

    if (sig_ok) {
        switch (ipv) {
            case 0:  fast_tile<0>(Xb, Ob, fp, fm, x0, y0, tx, ty, tid, smem); break;
            case 1:  fast_tile<1>(Xb, Ob, fp, fm, x0, y0, tx, ty, tid, smem); break;
            default: fast_tile<2>(Xb, Ob, fp, fm, x0, y0, tx, ty, tid, smem); break;
        }
    } else {
        for (int k = 0; k < ROWS; ++k)
            slow_pixel(Xb, Ob, sg, x0 + tx, y0 + ty * ROWS + k);
    }
}

extern "C" void kernel_launch(void* const* d_in, const int* in_sizes, int n_in,
                              void* d_out, int out_size, void* d_ws, size_t ws_size,
                              hipStream_t stream) {
    const float* x     = (const float*)d_in[0];
    const float* sigma = (const float*)d_in[1];
    float* out = (float*)d_out;

    dim3 grid(W_ / TCOLS, H_ / TROWS + 1, 4), block(64, 4);
    hipLaunchKernelGGL(st_kernel, grid, block, 0, stream, x, sigma, out);
}

// Round 3
// 113.034 us; speedup vs baseline: 1.0387x; 1.0204x over previous
//
#include <hip/hip_runtime.h>

// StructureTensorEffect: B=4, C=3, H=W=1024, fp32.
// Round 9: border-first dispatch. R7 (3-phase staging, 7 blk/CU) and R8
// (single-shot global_load_lds staging, 4 blk/CU, 1 barrier) measured
// IDENTICAL (44.7 vs 43.7us) -> staging latency is NOT the limiter.
// Avg occupancy ~21% (~1.7 waves/SIMD) with per-pipe work estimates all
// <= ~19us  => tail-heavy execution. The border slice (gather-heavy
// slow_pixel blocks, ~5-10us each of TA-issue: 3x72 scattered loads per
// thread, ~22 transactions/gather on x-border columns) was dispatched
// LAST (blockIdx.y == 32, i.e. at 24/49/74/99% of grid order per batch).
// Last-dispatched + slowest-block = additive tail. This round moves the
// border slice to blockIdx.y == 0 (dispatched first, overlaps under the
// fast-tile phase) and shifts tile bands to y-1. No change to any math,
// layout, or staging — grid-y remap only, for clean attribution.
// Staging (from R8): all 3 channels staged at once via
// __builtin_amdgcn_global_load_lds (16B/lane direct-to-LDS, LDS linear
// in group index = wave-uniform-base + lane*16; per-lane clamped GLOBAL
// address does border replication), one vmcnt(0)+barrier, then all-
// channel compute with no further barriers. LDS 3*38*72*4 = 32832B.
// Borders: R4-proven scheme (store mask + border slice slow_pixel).

#define W_ 1024
#define H_ 1024
#define PLANE (1 << 20)
#define TCOLS 64
#define TROWS 32
#define ROWS 8
#define LSTRIDE 72     // staged cols: x0-4 .. x0+67 (18 float4 groups)

__device__ __forceinline__ float lerp1(float a, float b, float f) {
    return fmaf(f, b - a, a);
}

// async 16B global->LDS copy (gfx950). Dest must be linear in lane order.
__device__ __forceinline__ void async_copy16(const float* g, float* s) {
    __builtin_amdgcn_global_load_lds(
        (const __attribute__((address_space(1))) unsigned int*)g,
        (__attribute__((address_space(3))) unsigned int*)s,
        16, 0, 0);
}

// Exact per-pixel reference path (any sigma, any border) — verified R1-R8.
__device__ void slow_pixel(const float* __restrict__ Xb, float* __restrict__ Ob,
                           float sg, int xi, int y)
{
    float imf = floorf(-sg), ipf = floorf(sg);
    float fm  = -sg - imf;
    float fp  =  sg - ipf;
    int   im  = (int)imf, ip = (int)ipf;

    int cm0 = min(max(xi + im, 0), W_ - 1), cm1 = min(cm0 + 1, W_ - 1);
    int cp0 = min(max(xi + ip, 0), W_ - 1), cp1 = min(cp0 + 1, W_ - 1);
    int rm0 = min(max(y + im, 0), H_ - 1),  rm1 = min(rm0 + 1, H_ - 1);
    int rp0 = min(max(y + ip, 0), H_ - 1),  rp1 = min(rp0 + 1, H_ - 1);

    int o_rm0 = rm0 << 10, o_rm1 = rm1 << 10;
    int o_rp0 = rp0 << 10, o_rp1 = rp1 << 10;
    int o_r0  = y   << 10;

    float oxx = 0.f, oyy = 0.f, oxy = 0.f;

    #pragma unroll
    for (int c = 0; c < 3; ++c) {
        const float* base = Xb + ((size_t)c << 20);

        float hm_m0 = lerp1(base[o_rm0 + cm0], base[o_rm0 + cm1], fm);
        float hm_m1 = lerp1(base[o_rm1 + cm0], base[o_rm1 + cm1], fm);
        float hm_0  = lerp1(base[o_r0  + cm0], base[o_r0  + cm1], fm);
        float hm_p0 = lerp1(base[o_rp0 + cm0], base[o_rp0 + cm1], fm);
        float hm_p1 = lerp1(base[o_rp1 + cm0], base[o_rp1 + cm1], fm);
        float hp_m0 = lerp1(base[o_rm0 + cp0], base[o_rm0 + cp1], fp);
        float hp_m1 = lerp1(base[o_rm1 + cp0], base[o_rm1 + cp1], fp);
        float hp_0  = lerp1(base[o_r0  + cp0], base[o_r0  + cp1], fp);
        float hp_p0 = lerp1(base[o_rp0 + cp0], base[o_rp0 + cp1], fp);
        float hp_p1 = lerp1(base[o_rp1 + cp0], base[o_rp1 + cp1], fp);
        float h0_m0 = base[o_rm0 + xi], h0_m1 = base[o_rm1 + xi];
        float h0_p0 = base[o_rp0 + xi], h0_p1 = base[o_rp1 + xi];

        float t0 = lerp1(hm_m0, hm_m1, fm);
        float t1 = hm_0;
        float t2 = lerp1(hm_p0, hm_p1, fp);
        float t3 = lerp1(h0_m0, h0_m1, fm);
        float t4 = lerp1(h0_p0, h0_p1, fp);
        float t5 = lerp1(hp_m0, hp_m1, fm);
        float t6 = hp_0;
        float t7 = lerp1(hp_p0, hp_p1, fp);

        float su = 0.25f * (t5 + t7 - t0 - t2) + 0.5f * (t6 - t1);
        float sv = 0.25f * (t2 + t7 - t0 - t5) + 0.5f * (t4 - t3);

        float l2 = (c == 0) ? 10000.f : 1.f;
        oxx = fmaf(l2 * su, su, oxx);
        oyy = fmaf(l2 * sv, sv, oyy);
        oxy = fmaf(l2 * su, sv, oxy);
    }

    int pix = (y << 10) | xi;
    Ob[pix]             = oxx;
    Ob[PLANE + pix]     = oyy;
    Ob[2 * PLANE + pix] = oxy;
}

template<int N>
__device__ __forceinline__ void acc(float (&arr)[N], int k, float val) {
    if (k >= 0 && k < N) arr[k] += val;   // k constant after unroll
}

// Fast tile: block covers cols x0..x0+63, rows y0..y0+31.
// Stage ALL channels' clamped windows (rows y0-IP-1..y0+32+IP, cols
// x0-4..x0+67) into LDS via async 16B copies, one barrier, then stream
// the accumulate from LDS for all 3 channels with no further barriers.
// Store mask (x>IP && x<1023-IP && y>IP) excludes the clamp-wrong px;
// those are covered by the border slice.
template<int IP>
__device__ void fast_tile(const float* __restrict__ Xb, float* __restrict__ Ob,
                          float fp, float fm, int x0, int y0,
                          int tx, int ty, int tid, float* smem)
{
    constexpr int LROWS  = TROWS + 2 * IP + 2;   // staged rows per channel
    constexpr int RW     = ROWS + 2 * IP + 2;    // window rows per thread
    constexpr int NG     = 3 * LROWS * 18;       // float4 groups, all channels
    constexpr int FULLIT = NG / 256;             // guard-free iterations

    int x = x0 + tx;
    int Y = y0 + ty * ROWS;

    auto stage = [&](int g) {
        int row  = g / 18;             // 0 .. 3*LROWS-1
        int grp  = g - row * 18;
        int c    = row / LROWS;
        int lrow = row - c * LROWS;
        int gr   = min(max(y0 - IP - 1 + lrow, 0), H_ - 1);
        int gc   = min(max(x0 - 4 + grp * 4, 0), W_ - 4);
        async_copy16(Xb + ((size_t)c << 20) + (gr << 10) + gc,
                     smem + g * 4);    // LDS linear in g: lane-contiguous
    };

    // ---- single-shot staging: all channels, direct-to-LDS ----
    #pragma unroll
    for (int it = 0; it < FULLIT; ++it)
        stage(it * 256 + tid);         // uniform exec
    if (FULLIT * 256 + tid < NG)       // single guarded tail copy
        stage(FULLIT * 256 + tid);

    __syncthreads();   // compiler emits vmcnt(0) drain before s_barrier

    float oxx[ROWS], oyy[ROWS], oxy[ROWS];
    #pragma unroll
    for (int k = 0; k < ROWS; ++k) { oxx[k] = 0.f; oyy[k] = 0.f; oxy[k] = 0.f; }

    // thread's LDS read base: window row w of channel c lives at LDS row
    // c*LROWS + ty*ROWS + w; LDS col of global col gcol is gcol-(x0-4);
    // a0 is at col x-IP-1 -> tx + 3 - IP.
    const float* spb = smem + (ty * ROWS) * LSTRIDE + tx + (3 - IP);

    #pragma unroll
    for (int c = 0; c < 3; ++c) {
        const float* sp = spb + c * (LROWS * LSTRIDE);

        float su[ROWS], sv[ROWS];
        #pragma unroll
        for (int k = 0; k < ROWS; ++k) { su[k] = 0.f; sv[k] = 0.f; }

        #pragma unroll
        for (int w = 0; w < RW; ++w) {
            float a0 = sp[w * LSTRIDE];
            float a1 = sp[w * LSTRIDE + 1];
            float cc = sp[w * LSTRIDE + IP + 1];
            float b0 = sp[w * LSTRIDE + 2 * IP + 1];
            float b1 = sp[w * LSTRIDE + 2 * IP + 2];
            float hm = lerp1(a0, a1, fm);
            float hp = lerp1(b0, b1, fp);
            float q  = hp - hm;
            float A  = 0.25f * q;
            float hq = 0.5f  * q;
            float Bv = fmaf(0.25f, hm + hp, 0.5f * cc);
            float fpA = fp * A,  fmA = fm * A;
            float fpB = fp * Bv, fmB = fm * Bv;

            acc(su, w,              fpA);
            acc(su, w - 1,          fmA);
            acc(su, w - IP - 1,     hq);
            acc(su, w - 2*IP - 1,   fmA);
            acc(su, w - 2*IP - 2,   fpA);
            acc(sv, w,             -fpB);
            acc(sv, w - 1,         -fmB);
            acc(sv, w - 2*IP - 1,   fmB);
            acc(sv, w - 2*IP - 2,   fpB);
        }

        float l2 = (c == 0) ? 10000.f : 1.f;
        #pragma unroll
        for (int k = 0; k < ROWS; ++k) {
            oxx[k] = fmaf(l2 * su[k], su[k], oxx[k]);
            oyy[k] = fmaf(l2 * sv[k], sv[k], oyy[k]);
            oxy[k] = fmaf(l2 * su[k], sv[k], oxy[k]);
        }
    }

    bool okx = (x > IP) && (x < W_ - 1 - IP);
    #pragma unroll
    for (int k = 0; k < ROWS; ++k) {
        int y = Y + k;
        if (okx && y > IP) {
            int pix = (y << 10) | x;
            Ob[pix]             = oxx[k];
            Ob[PLANE + pix]     = oyy[k];
            Ob[2 * PLANE + pix] = oxy[k];
        }
    }
}

// block (64,4). grid.y = 1 border slice (FIRST) + 32 tile bands.
__global__ __launch_bounds__(256) void st_kernel(
    const float* __restrict__ X, const float* __restrict__ S,
    float* __restrict__ O)
{
    int b  = blockIdx.z;
    const float* Xb = X + (size_t)b * 3 * PLANE;
    float*       Ob = O + (size_t)b * 3 * PLANE;
    float sg = S[b];

    int tx = threadIdx.x, ty = threadIdx.y;
    int tid = ty * 64 + tx;

    if (blockIdx.y == 0) {
        // Border slice, dispatched FIRST so its gather-heavy blocks
        // overlap under the fast-tile phase instead of forming a tail.
        // x in {0,1,2,1021,1022,1023} all y (6144 px) plus y in {0,1,2}
        // all x (3072 px). 16*256 = 4096 threads -> 3 iters.
        int t = blockIdx.x * 256 + tid;
        #pragma unroll
        for (int it = 0; it < 3; ++it) {
            int pidx = t + it * 4096;
            if (pidx < 6144) {
                int yy = pidx / 6;
                int cc = pidx - yy * 6;
                int xx = (cc < 3) ? cc : (W_ - 6 + cc);
                slow_pixel(Xb, Ob, sg, xx, yy);
            } else if (pidx < 9216) {
                int p2 = pidx - 6144;
                slow_pixel(Xb, Ob, sg, p2 & 1023, p2 >> 10);
            }
        }
        return;
    }

    int x0 = blockIdx.x * TCOLS;
    int y0 = (blockIdx.y - 1) * TROWS;

    int ipv = (int)floorf(sg);
    int imv = (int)floorf(-sg);
    bool sig_ok = (imv == -ipv - 1) && ipv >= 0 && ipv <= 2;  // block-uniform
    float fp = sg - (float)ipv;
    float fm = 1.0f - fp;

    // worst case IP=2: 3 channels x 38 rows x 72 cols = 32832 B -> 4 blk/CU
    __shared__ float smem[3 * (TROWS + 6) * LSTRIDE];

    if (sig_ok) {
        switch (ipv) {
            case 0:  fast_tile<0>(Xb, Ob, fp, fm, x0, y0, tx, ty, tid, smem); break;
            case 1:  fast_tile<1>(Xb, Ob, fp, fm, x0, y0, tx, ty, tid, smem); break;
            default: fast_tile<2>(Xb, Ob, fp, fm, x0, y0, tx, ty, tid, smem); break;
        }
    } else {
        for (int k = 0; k < ROWS; ++k)
            slow_pixel(Xb, Ob, sg, x0 + tx, y0 + ty * ROWS + k);
    }
}

extern "C" void kernel_launch(void* const* d_in, const int* in_sizes, int n_in,
                              void* d_out, int out_size, void* d_ws, size_t ws_size,
                              hipStream_t stream) {
    const float* x     = (const float*)d_in[0];
    const float* sigma = (const float*)d_in[1];
    float* out = (float*)d_out;

    dim3 grid(W_ / TCOLS, H_ / TROWS + 1, 4), block(64, 4);
    hipLaunchKernelGGL(st_kernel, grid, block, 0, stream, x, sigma, out);
}